// Round 7
// baseline (465.750 us; speedup 1.0000x reference)
//
#include <hip/hip_runtime.h>
#include <math.h>
#include <stdint.h>

#define V_N 100000
#define E_N 300000
#define D_N 128
#define EPSV 1e-5f
#define NCHUNK 391   // ceil(V_N/256)
#define MPAD 100096  // 1564 * 64

typedef _Float16 f16;
typedef f16 f16x8 __attribute__((ext_vector_type(8)));
typedef f16 f16x4 __attribute__((ext_vector_type(4)));
typedef f16 f16x2 __attribute__((ext_vector_type(2)));
typedef float f32x4 __attribute__((ext_vector_type(4)));

// async global->LDS, 16B per lane; lds base must be wave-uniform
#define GLD(g, l) __builtin_amdgcn_global_load_lds( \
    (__attribute__((address_space(1))) void*)(g),   \
    (__attribute__((address_space(3))) void*)(l), 16, 0, 0)

// ----------------- CSR build -----------------
__global__ __launch_bounds__(256) void k_count(const int* __restrict__ edges, int* __restrict__ deg) {
  int i = blockIdx.x * blockDim.x + threadIdx.x;
  if (i < 2 * E_N) atomicAdd(&deg[edges[i]], 1);
}

__global__ __launch_bounds__(256) void k_chunksum(const int* __restrict__ deg, int* __restrict__ csum) {
  __shared__ int red[256];
  int c = blockIdx.x, t = threadIdx.x;
  int i = c * 256 + t;
  red[t] = (i < V_N) ? deg[i] : 0;
  __syncthreads();
  for (int s = 128; s > 0; s >>= 1) {
    if (t < s) red[t] += red[t + s];
    __syncthreads();
  }
  if (t == 0) csum[c] = red[0];
}

__global__ __launch_bounds__(512) void k_scanchunks(const int* __restrict__ csum, int* __restrict__ coff) {
  __shared__ int sh[512];
  int t = threadIdx.x;
  int v = (t < NCHUNK) ? csum[t] : 0;
  sh[t] = v;
  __syncthreads();
  for (int s = 1; s < 512; s <<= 1) {
    int x = (t >= s) ? sh[t - s] : 0;
    __syncthreads();
    sh[t] += x;
    __syncthreads();
  }
  if (t < NCHUNK) coff[t] = sh[t] - v;  // exclusive
}

__global__ __launch_bounds__(256) void k_writeoff(const int* __restrict__ deg, const int* __restrict__ coff,
                                                  int* __restrict__ csr_off, float* __restrict__ dinv,
                                                  float* __restrict__ degf) {
  __shared__ int sh[256];
  int c = blockIdx.x, t = threadIdx.x;
  int i = c * 256 + t;
  int v = (i < V_N) ? deg[i] : 0;
  sh[t] = v;
  __syncthreads();
  for (int s = 1; s < 256; s <<= 1) {
    int x = (t >= s) ? sh[t - s] : 0;
    __syncthreads();
    sh[t] += x;
    __syncthreads();
  }
  int excl = sh[t] - v;
  if (i <= V_N) csr_off[i] = coff[c] + excl;
  if (i < V_N) {
    dinv[i] = 1.0f / (1.0f + (float)v);
    degf[i] = (float)v;
  }
}

__global__ __launch_bounds__(256) void k_fill(const int* __restrict__ edges, const int* __restrict__ csr_off,
                                              int* __restrict__ cursor, int* __restrict__ adj) {
  int e = blockIdx.x * blockDim.x + threadIdx.x;
  if (e >= E_N) return;
  int s = edges[2 * e], d = edges[2 * e + 1];
  int p = atomicAdd(&cursor[s], 1);
  adj[csr_off[s] + p] = d;
  int q = atomicAdd(&cursor[d], 1);
  adj[csr_off[d] + q] = s;
}

// ----------------- weight prep: Wcat[l][n][k] half, k = [W0 row | W1 row] -----------------
__global__ __launch_bounds__(256) void k_prepw(const float* __restrict__ W0, const float* __restrict__ W1,
                                               f16* __restrict__ Wc) {
  int idx = blockIdx.x * 256 + threadIdx.x;
  if (idx >= 3 * 128 * 256) return;
  int l = idx >> 15;
  int rem = idx & 32767;
  int n = rem >> 8, k = rem & 255;
  float v = (k < 128) ? W0[l * 16384 + n * 128 + k] : W1[l * 16384 + n * 128 + (k - 128)];
  Wc[idx] = (f16)v;
}

// ----------------- cast: y[v] = f16(features[v]); blocks 0..63 zero stats shards ----------
__global__ __launch_bounds__(256) void k_cast(const float* __restrict__ x, f16* __restrict__ y,
                                              float* __restrict__ stats) {
  if (blockIdx.x < 64) stats[blockIdx.x * 256 + threadIdx.x] = 0.f;
  int q = blockIdx.x * 256 + threadIdx.x;  // float4 index over V_N*128
  if (q >= V_N * 32) return;
  float4 xv = ((const float4*)x)[q];
  f16x4 h;
  h[0] = (f16)xv.x; h[1] = (f16)xv.y; h[2] = (f16)xv.z; h[3] = (f16)xv.w;
  *(f16x4*)&y[(size_t)q * 4] = h;
}

// ----------------- fused gather + GEMM + BN stats -----------------
// Per block: 64 rows. Assemble A-tile in LDS: A0 = own activation rows, A1 = neighbor agg.
// Then t = dinv*([A0|A1] @ Wcat^T + b0 + deg*b1), written f16 to tout, with sharded stats.
// MODE 0: A0 <- y (GLD), neighbors from y raw.              (tin unused)
// MODE 1: A0 <- relu(scale*t_in+shift) (ds_write), neighbors from tin with affine on the fly.
// RACE NOTE: tin and tout MUST be different buffers (ping-pong) — neighbor reads span the
// whole vertex range while other blocks write tout.
// LDS swizzle (A0/A1, 16B chunks, 16 chunks/row): elem (r, c) chunk ch=c>>3 stored at
// slot r*16 + ((ch&8) | ((ch&7)^(r&7))). Bs per-K-chunk: slot r*8 + (c^(r&7)).
template <int MODE>
__global__ __launch_bounds__(256, 3) void k_fused(
    const f16* __restrict__ ytab, const f16* __restrict__ tin, const f16* __restrict__ Wc,
    const float* __restrict__ b0, const float* __restrict__ b1,
    const float* __restrict__ dinv, const float* __restrict__ degf,
    const int* __restrict__ csr_off, const int* __restrict__ adj,
    const float* __restrict__ scale, const float* __restrict__ shift,
    f16* __restrict__ tout, float* __restrict__ stats) {
  __shared__ __align__(16) f16 A0[64 * 128];
  __shared__ __align__(16) f16 A1[64 * 128];
  __shared__ __align__(16) f16 Bs[128 * 64];
  __shared__ float sstat[256];
  int tid = threadIdx.x;
  int w = tid >> 6, lane = tid & 63;
  int quad = lane >> 4, l16 = lane & 15;
  int row0 = blockIdx.x * 64;
  sstat[tid] = 0.f;

  // prefetch B K-chunk 0 (drains at the post-gather barrier -> free overlap)
#pragma unroll
  for (int i = 0; i < 4; ++i) {
    int s = (w * 4 + i) * 64 + lane;
    int r = s >> 3, c = (s & 7) ^ (r & 7);
    GLD(Wc + (size_t)r * 256 + c * 8, &Bs[(w * 4 + i) * 512]);
  }

  const f16* base = MODE ? tin : ytab;
  int c0 = lane * 2;
  int chq = lane >> 2;          // 0..15: chunk of this lane's f16x2
  int cof = (lane & 3) * 2;     // within-chunk f16 offset
  f16x2 scv = {}, sfv = {}, zero = {};
  if (MODE) {
    scv[0] = (f16)scale[c0]; scv[1] = (f16)scale[c0 + 1];
    sfv[0] = (f16)shift[c0]; sfv[1] = (f16)shift[c0 + 1];
  }

  // ---- A0: own activation rows ----
  if (MODE == 0) {
#pragma unroll
    for (int i = 0; i < 4; ++i) {
      int s = (w * 4 + i) * 64 + lane;
      int r = s >> 4, cq = s & 15;
      int ch = (cq & 8) | ((cq & 7) ^ (r & 7));
      GLD(ytab + (size_t)(row0 + r) * 128 + ch * 8, &A0[(w * 4 + i) * 512]);
    }
  } else {
    f16x2 ov[16];
#pragma unroll
    for (int i = 0; i < 16; ++i)
      ov[i] = *(const f16x2*)&tin[(size_t)(row0 + w * 16 + i) * 128 + c0];
#pragma unroll
    for (int i = 0; i < 16; ++i) {
      int r = w * 16 + i;
      f16x2 yv = __builtin_elementwise_max(scv * ov[i] + sfv, zero);
      int slot = r * 16 + ((chq & 8) | ((chq & 7) ^ (r & 7)));
      *(f16x2*)&A0[slot * 8 + cof] = yv;
    }
  }

  // ---- A1: neighbor aggregate (gather), 2 batches of 8 rows x 8 slots = 64 outstanding ----
#pragma unroll
  for (int b = 0; b < 2; ++b) {
    int sE[8], eE[8];
#pragma unroll
    for (int i = 0; i < 8; ++i) {
      int v = row0 + w * 16 + b * 8 + i;
      int s_ = 0, e_ = 0;
      if (v < V_N) { s_ = csr_off[v]; e_ = csr_off[v + 1]; }
      sE[i] = s_; eE[i] = e_;
    }
    int idx[8][8];
#pragma unroll
    for (int i = 0; i < 8; ++i) {
      int last = eE[i] - 1;
      if (last < sE[i]) last = sE[i];  // e==s==0 -> adj[0] (masked out below)
#pragma unroll
      for (int j = 0; j < 8; ++j) {
        int pp = sE[i] + j;
        idx[i][j] = adj[pp < eE[i] ? pp : last];
      }
    }
    f16x2 hh[8][8];
#pragma unroll
    for (int i = 0; i < 8; ++i)
#pragma unroll
      for (int j = 0; j < 8; ++j)
        hh[i][j] = *(const f16x2*)&base[(size_t)idx[i][j] * 128 + c0];
#pragma unroll
    for (int i = 0; i < 8; ++i) {
#pragma unroll
      for (int j = 0; j < 8; ++j) {
        f16x2 u = hh[i][j];
        if (MODE) u = __builtin_elementwise_max(scv * u + sfv, zero);
        hh[i][j] = (sE[i] + j < eE[i]) ? u : zero;
      }
      f16x2 t01 = hh[i][0] + hh[i][1], t23 = hh[i][2] + hh[i][3];
      f16x2 t45 = hh[i][4] + hh[i][5], t67 = hh[i][6] + hh[i][7];
      f16x2 sum = (t01 + t23) + (t45 + t67);
      float a0 = (float)sum[0], a1 = (float)sum[1];
      // tail for deg > 8 (wave-uniform trip count)
      for (int p = sE[i] + 8; p < eE[i]; p += 8) {
        int id2[8];
#pragma unroll
        for (int j = 0; j < 8; ++j) {
          int pp = p + j;
          id2[j] = adj[pp < eE[i] ? pp : eE[i] - 1];
        }
        f16x2 g[8];
#pragma unroll
        for (int j = 0; j < 8; ++j) g[j] = *(const f16x2*)&base[(size_t)id2[j] * 128 + c0];
#pragma unroll
        for (int j = 0; j < 8; ++j) {
          f16x2 u = g[j];
          if (MODE) u = __builtin_elementwise_max(scv * u + sfv, zero);
          g[j] = (p + j < eE[i]) ? u : zero;
        }
        f16x2 u01 = g[0] + g[1], u23 = g[2] + g[3];
        f16x2 u45 = g[4] + g[5], u67 = g[6] + g[7];
        f16x2 us = (u01 + u23) + (u45 + u67);
        a0 += (float)us[0];
        a1 += (float)us[1];
      }
      int r = w * 16 + b * 8 + i;
      f16x2 o;
      o[0] = (f16)a0; o[1] = (f16)a1;
      int slot = r * 16 + ((chq & 8) | ((chq & 7) ^ (r & 7)));
      *(f16x2*)&A1[slot * 8 + cof] = o;
    }
  }
  __syncthreads();  // A0/A1 assembled; Bs(0) GLD drained

  // ---- K-loop: 4 chunks of 64 ----
  f32x4 acc[8] = {};
  for (int kc = 0; kc < 4; ++kc) {
    const f16* Aa = (kc < 2) ? A0 : A1;
    int colb = (kc & 1) * 64;
#pragma unroll
    for (int ks = 0; ks < 2; ++ks) {
      int colA = colb + ks * 32 + quad * 8;
      int ch = colA >> 3;
      int rr = w * 16 + l16;
      int slotA = rr * 16 + ((ch & 8) | ((ch & 7) ^ (rr & 7)));
      f16x8 af = *(const f16x8*)&Aa[slotA * 8];
      int cc = ks * 4 + quad;
#pragma unroll
      for (int ni = 0; ni < 8; ++ni) {
        int rb = ni * 16 + l16;
        f16x8 bf = *(const f16x8*)&Bs[(rb * 8 + (cc ^ (rb & 7))) * 8];
        acc[ni] = __builtin_amdgcn_mfma_f32_16x16x32_f16(af, bf, acc[ni], 0, 0, 0);
      }
    }
    if (kc < 3) {
      __syncthreads();  // all waves done reading Bs
#pragma unroll
      for (int i = 0; i < 4; ++i) {
        int s = (w * 4 + i) * 64 + lane;
        int r = s >> 3, c = (s & 7) ^ (r & 7);
        GLD(Wc + (size_t)r * 256 + (kc + 1) * 64 + c * 8, &Bs[(w * 4 + i) * 512]);
      }
      __syncthreads();
    }
  }

  // ---- epilogue: t-write + BN stats. C/D layout: col = l16, row = quad*4 + reg ----
  float b0c[8], b1c[8];
#pragma unroll
  for (int ni = 0; ni < 8; ++ni) {
    b0c[ni] = b0[ni * 16 + l16];
    b1c[ni] = b1[ni * 16 + l16];
  }
  float csum[8] = {}, csq[8] = {};
#pragma unroll
  for (int reg = 0; reg < 4; ++reg) {
    int v = row0 + w * 16 + quad * 4 + reg;
    if (v < V_N) {
      float dv = dinv[v], gf = degf[v];
#pragma unroll
      for (int ni = 0; ni < 8; ++ni) {
        float tv = dv * (acc[ni][reg] + b0c[ni] + gf * b1c[ni]);
        tout[(size_t)v * 128 + ni * 16 + l16] = (f16)tv;
        csum[ni] += tv;
        csq[ni] += tv * tv;
      }
    }
  }
#pragma unroll
  for (int ni = 0; ni < 8; ++ni) {
    csum[ni] += __shfl_xor(csum[ni], 16);
    csum[ni] += __shfl_xor(csum[ni], 32);
    csq[ni] += __shfl_xor(csq[ni], 16);
    csq[ni] += __shfl_xor(csq[ni], 32);
  }
  if (quad == 0) {
#pragma unroll
    for (int ni = 0; ni < 8; ++ni) {
      atomicAdd(&sstat[ni * 16 + l16], csum[ni]);
      atomicAdd(&sstat[128 + ni * 16 + l16], csq[ni]);
    }
  }
  __syncthreads();
  atomicAdd(&stats[(blockIdx.x & 63) * 256 + tid], sstat[tid]);  // 64-way sharded
}

// ----------------- finalize BN affine; then zero stats for the next layer -----------------
__global__ __launch_bounds__(256) void k_finalize(float* __restrict__ stats, const float* __restrict__ gamma,
                                                  const float* __restrict__ beta, float* __restrict__ scale,
                                                  float* __restrict__ shift) {
  int d = threadIdx.x;
  if (d < 128) {
    float s = 0.f, sq = 0.f;
#pragma unroll 8
    for (int h = 0; h < 64; ++h) {
      s += stats[h * 256 + d];
      sq += stats[h * 256 + 128 + d];
    }
    float mu = s * (1.0f / V_N);
    float var = sq * (1.0f / V_N) - mu * mu;
    float scv = gamma[d] * rsqrtf(var + EPSV);
    scale[d] = scv;
    shift[d] = beta[d] - mu * scv;
  }
  __syncthreads();
#pragma unroll 4
  for (int h = 0; h < 64; ++h) stats[h * 256 + threadIdx.x] = 0.f;
}

// ----------------- final: out = relu(scale*t + shift + features) -----------------
__global__ __launch_bounds__(256) void k_final(const f16* __restrict__ t, const float* __restrict__ feat,
                                               const float* __restrict__ scale, const float* __restrict__ shift,
                                               float* __restrict__ out) {
  int q = blockIdx.x * 256 + threadIdx.x;  // float4 index
  if (q >= V_N * 32) return;
  int c4 = q & 31;
  f16x4 tv = *(const f16x4*)&t[(size_t)q * 4];
  float4 fv = ((const float4*)feat)[q];
  float4 sc = ((const float4*)scale)[c4];
  float4 sf = ((const float4*)shift)[c4];
  float4 o;
  o.x = fmaxf(sc.x * (float)tv[0] + sf.x + fv.x, 0.f);
  o.y = fmaxf(sc.y * (float)tv[1] + sf.y + fv.y, 0.f);
  o.z = fmaxf(sc.z * (float)tv[2] + sf.z + fv.z, 0.f);
  o.w = fmaxf(sc.w * (float)tv[3] + sf.w + fv.w, 0.f);
  ((float4*)out)[q] = o;
}

extern "C" void kernel_launch(void* const* d_in, const int* in_sizes, int n_in,
                              void* d_out, int out_size, void* d_ws, size_t ws_size,
                              hipStream_t stream) {
  const float* features = (const float*)d_in[0];
  const int* edges = (const int*)d_in[1];
  const float* W0 = (const float*)d_in[2];
  const float* b0 = (const float*)d_in[3];
  const float* W1 = (const float*)d_in[4];
  const float* b1 = (const float*)d_in[5];
  const float* gamma = (const float*)d_in[6];
  const float* beta = (const float*)d_in[7];
  float* out = (float*)d_out;

  char* ws = (char*)d_ws;
  size_t off = 0;
  auto alloc = [&](size_t bytes) -> void* {
    void* p = ws + off;
    off = (off + bytes + 255) & ~(size_t)255;
    return p;
  };
  int* deg = (int*)alloc((size_t)V_N * 4);
  int* csr_off = (int*)alloc((size_t)(V_N + 1) * 4);
  int* adj = (int*)alloc((size_t)2 * E_N * 4);
  float* dinv = (float*)alloc((size_t)V_N * 4);
  float* degf = (float*)alloc((size_t)V_N * 4);
  int* csum = (int*)alloc(512 * 4);
  int* coff = (int*)alloc(512 * 4);
  float* stats = (float*)alloc(64 * 256 * 4);
  float* scale = (float*)alloc(128 * 4);
  float* shift = (float*)alloc(128 * 4);
  f16* y = (f16*)alloc((size_t)MPAD * 128 * 2);
  f16* tA = (f16*)alloc((size_t)MPAD * 128 * 2);
  f16* tB = (f16*)alloc((size_t)MPAD * 128 * 2);
  f16* Wcat = (f16*)alloc((size_t)3 * 128 * 256 * 2);

  // CSR + dinv/degf
  hipMemsetAsync(deg, 0, (size_t)V_N * 4, stream);
  k_count<<<(2 * E_N + 255) / 256, 256, 0, stream>>>(edges, deg);
  k_chunksum<<<NCHUNK, 256, 0, stream>>>(deg, csum);
  k_scanchunks<<<1, 512, 0, stream>>>(csum, coff);
  k_writeoff<<<NCHUNK, 256, 0, stream>>>(deg, coff, csr_off, dinv, degf);
  hipMemsetAsync(deg, 0, (size_t)V_N * 4, stream);
  k_fill<<<(E_N + 255) / 256, 256, 0, stream>>>(edges, csr_off, deg, adj);
  k_prepw<<<384, 256, 0, stream>>>(W0, W1, Wcat);
  k_cast<<<12500, 256, 0, stream>>>(features, y, stats);

  // layer 0: y -> tA   (MODE 0; tin unused)
  k_fused<0><<<MPAD / 64, 256, 0, stream>>>(y, tA, Wcat, b0, b1, dinv, degf,
                                            csr_off, adj, scale, shift, tA, stats);
  k_finalize<<<1, 256, 0, stream>>>(stats, gamma, beta, scale, shift);
  // layer 1: tA -> tB  (ping-pong: tin != tout, required for correctness)
  k_fused<1><<<MPAD / 64, 256, 0, stream>>>(y, tA, Wcat + (size_t)1 * 128 * 256,
                                            b0 + 1 * D_N, b1 + 1 * D_N, dinv, degf,
                                            csr_off, adj, scale, shift, tB, stats);
  k_finalize<<<1, 256, 0, stream>>>(stats, gamma + 1 * D_N, beta + 1 * D_N, scale, shift);
  // layer 2: tB -> tA
  k_fused<1><<<MPAD / 64, 256, 0, stream>>>(y, tB, Wcat + (size_t)2 * 128 * 256,
                                            b0 + 2 * D_N, b1 + 2 * D_N, dinv, degf,
                                            csr_off, adj, scale, shift, tA, stats);
  k_finalize<<<1, 256, 0, stream>>>(stats, gamma + 2 * D_N, beta + 2 * D_N, scale, shift);

  k_final<<<12500, 256, 0, stream>>>(tA, features, scale, shift, out);
}